// Round 2
// baseline (315.978 us; speedup 1.0000x reference)
//
#include <hip/hip_runtime.h>
#include <cstdint>
#include <cstddef>

// ---- types ----
typedef unsigned short u16;
typedef float  f32x4  __attribute__((ext_vector_type(4)));
typedef __bf16 bf16x8 __attribute__((ext_vector_type(8)));
typedef unsigned short us8 __attribute__((ext_vector_type(8)));
typedef unsigned short us4 __attribute__((ext_vector_type(4)));
typedef float  f32x4v __attribute__((ext_vector_type(4)));
typedef unsigned int u32x2 __attribute__((ext_vector_type(2)));

#define AS1 __attribute__((address_space(1)))
#define AS3 __attribute__((address_space(3)))

// fp32 -> bf16 round-to-nearest-even (scalar)
__device__ __forceinline__ u16 f2b(float f) {
  unsigned u = __float_as_uint(f);
  u += 0x7FFFu + ((u >> 16) & 1u);
  return (u16)(u >> 16);
}

// pack two fp32 -> bf16x2 dword (round-half-up; a = low 16, b = high 16)
__device__ __forceinline__ unsigned pkbf(float a, float b) {
  unsigned ua = __float_as_uint(a) + 0x8000u;
  unsigned ub = __float_as_uint(b) + 0x8000u;
  return __builtin_amdgcn_perm(ub, ua, 0x07060302u);
}

__device__ __forceinline__ bf16x8 ldfrag(const u16* p) {
  us8 v = *(const us8*)p;
  return __builtin_bit_cast(bf16x8, v);
}

__device__ __forceinline__ f32x4 mfma16(bf16x8 a, bf16x8 b, f32x4 c) {
  return __builtin_amdgcn_mfma_f32_16x16x32_bf16(a, b, c, 0, 0, 0);
}

// async global->LDS, 16B per lane; lds base must be wave-uniform (lane*16 auto-added)
__device__ __forceinline__ void gl_lds16(const u16* g, AS3 u16* l) {
  __builtin_amdgcn_global_load_lds((AS1 void*)g, (AS3 void*)l, 16, 0, 0);
}

#define BAR()  do { __builtin_amdgcn_s_barrier(); __builtin_amdgcn_sched_barrier(0); } while (0)
#define WLG()  do { __asm__ volatile("s_waitcnt lgkmcnt(0)" ::: "memory"); __builtin_amdgcn_sched_barrier(0); } while (0)
#define WVM4() do { __asm__ volatile("s_waitcnt vmcnt(4)" ::: "memory"); __builtin_amdgcn_sched_barrier(0); } while (0)
#define WVM0() do { __asm__ volatile("s_waitcnt vmcnt(0)" ::: "memory"); __builtin_amdgcn_sched_barrier(0); } while (0)

// ---- fused cast: x + all 4 weights, one launch. grid 12288 x 256 ----
__global__ __launch_bounds__(256) void cvt_all(
    const float* __restrict__ x,
    const float* __restrict__ Wq, const float* __restrict__ Wk,
    const float* __restrict__ Wv, const float* __restrict__ Wo,
    u16* __restrict__ xb, u16* __restrict__ Wqkv, u16* __restrict__ Wob) {
  int blk = blockIdx.x;
  const float* s;
  u16* d;
  int i;
  if (blk < 8192)       { s = x;  d = xb;             i = blk * 256 + threadIdx.x; }
  else if (blk < 9216)  { s = Wq; d = Wqkv;           i = (blk - 8192) * 256 + threadIdx.x; }
  else if (blk < 10240) { s = Wk; d = Wqkv + 1048576; i = (blk - 9216) * 256 + threadIdx.x; }
  else if (blk < 11264) { s = Wv; d = Wqkv + 2097152; i = (blk - 10240) * 256 + threadIdx.x; }
  else                  { s = Wo; d = Wob;            i = (blk - 11264) * 256 + threadIdx.x; }
  f32x4v f = ((const f32x4v*)s)[i];
  us4 o = { f2b(f[0]), f2b(f[1]), f2b(f[2]), f2b(f[3]) };
  ((us4*)d)[i] = o;
}

// ---- GEMM1: C = X @ Wqkv^T -> Q (prescaled), K, Vt.
// R9: 8-phase 256x256/BK=64 template (T2+T3+T4+T5, guide §5). 8 waves (2Mx4N),
// per-wave 128x64 output, acc[8][4]. LDS 128 KiB = 2 buf x {A: 2x128x64, B:
// 2x128x64} in 8 half-tile slots of 8192 u16. Granule swizzle pos = g^(r&7)
// (2-way max on ds_read_b128); global source pre-swizzled so global_load_lds
// dest stays linear (rule #21). Quadrant zigzag (0,0)->(0,1)->(1,1)->(1,0)
// confines slot reads: B-slots die at P1/P5, A-slots at P2/P6; each phase
// stages exactly the slot that died >=1 phase earlier:
//   P0:A0(2i+1) P1:A1(2i+1) P2:B0(2i+2) P3:B1(2i+2)
//   P4:A0(2i+2) P5:A1(2i+2) P6:B0(2i+3) P7:B1(2i+3)
// Counted vmcnt(4) (=2 half-tiles in flight) at P3/P7 end only; drain at i=7.
// grid 384 (32x12), XCD-bijective swizzle (384%8==0).
__global__ __launch_bounds__(512, 2) void gemm_qkv(
    const u16* __restrict__ A, const u16* __restrict__ W,
    u16* __restrict__ Qb, u16* __restrict__ Kb, u16* __restrict__ Vt) {
  __shared__ u16 lds[65536];  // 128 KiB
  const int tid = threadIdx.x;
  const int lane = tid & 63, wave = tid >> 6;
  const int quad = lane >> 4, l16 = lane & 15;
  const int wm = wave >> 2, wn = wave & 3;

  int bid = blockIdx.x;
  int swz = ((bid & 7) * 48) + (bid >> 3);
  int by = swz / 12;
  int bx = swz - by * 12;
  const int m0 = by * 256, n0 = bx * 256;
  const int sec = n0 >> 10;  // 0=Q 1=K 2=V (256 | 1024 -> uniform per block)

  AS3 u16* lds3 = (AS3 u16*)lds;

  // staging: thread stages granules tid and tid+512 of one 128x64 half-tile.
  // dest granule G = l*512+tid (linear); its (row,pos) = (G>>3, G&7); logical
  // granule g = pos ^ (row&7) -> source col offset g*8 u16.
  const int gsw = (((tid & 7) ^ ((tid >> 3) & 7)) * 8);
  const int srow = tid >> 3;  // 0..63 (+64 for second load)
  const u16* gA = A + (size_t)(m0 + srow) * 1024 + gsw;
  const u16* gB = W + (size_t)(n0 + srow) * 1024 + gsw;
  const int dst = wave * 512;

  // reader: frag at (row r, k32, quad) -> stored pos = (k32*4+quad)^(r&7);
  // r = <mult of 16> + l16 so r&7 == l16&7.
  const int p0 = ((quad) ^ (l16 & 7)) * 8;
  const int p1 = ((4 + quad) ^ (l16 & 7)) * 8;
  const u16* rdA = lds + wm * 8192 + l16 * 64;
  const u16* rdB = lds + 16384 + (wn >> 1) * 8192 + ((wn & 1) * 64 + l16) * 64;

#define STAGE_A(kt, h) do {                                             \
    const u16* s_ = gA + (size_t)(h) * (128 * 1024) + (kt) * 64;        \
    int d_ = (((kt) & 1) * 32768) + (h) * 8192 + dst;                   \
    gl_lds16(s_, lds3 + d_);                                            \
    gl_lds16(s_ + 64 * 1024, lds3 + d_ + 4096);                         \
  } while (0)
#define STAGE_B(kt, h) do {                                             \
    const u16* s_ = gB + (size_t)(h) * (128 * 1024) + (kt) * 64;        \
    int d_ = (((kt) & 1) * 32768) + 16384 + (h) * 8192 + dst;           \
    gl_lds16(s_, lds3 + d_);                                            \
    gl_lds16(s_ + 64 * 1024, lds3 + d_ + 4096);                         \
  } while (0)
#define RDA(qm, bufo)                                                   \
  _Pragma("unroll") for (int t_ = 0; t_ < 4; t_++) {                    \
    aF[t_][0] = ldfrag(rdA + (bufo) + ((qm) * 4 + t_) * 1024 + p0);     \
    aF[t_][1] = ldfrag(rdA + (bufo) + ((qm) * 4 + t_) * 1024 + p1);     \
  }
#define RDB(BV, qn, bufo)                                               \
  _Pragma("unroll") for (int u_ = 0; u_ < 2; u_++) {                    \
    BV[u_][0] = ldfrag(rdB + (bufo) + ((qn) * 2 + u_) * 1024 + p0);     \
    BV[u_][1] = ldfrag(rdB + (bufo) + ((qn) * 2 + u_) * 1024 + p1);     \
  }
#define MM(qm, qn, BV) do {                                             \
    __builtin_amdgcn_s_setprio(1);                                      \
    if (sec != 2) {                                                     \
      _Pragma("unroll") for (int t_ = 0; t_ < 4; t_++)                  \
      _Pragma("unroll") for (int u_ = 0; u_ < 2; u_++) {                \
        acc[(qm)*4+t_][(qn)*2+u_] =                                     \
          mfma16(aF[t_][0], BV[u_][0], acc[(qm)*4+t_][(qn)*2+u_]);      \
        acc[(qm)*4+t_][(qn)*2+u_] =                                     \
          mfma16(aF[t_][1], BV[u_][1], acc[(qm)*4+t_][(qn)*2+u_]);      \
      }                                                                 \
    } else {                                                            \
      _Pragma("unroll") for (int t_ = 0; t_ < 4; t_++)                  \
      _Pragma("unroll") for (int u_ = 0; u_ < 2; u_++) {                \
        acc[(qm)*4+t_][(qn)*2+u_] =                                     \
          mfma16(BV[u_][0], aF[t_][0], acc[(qm)*4+t_][(qn)*2+u_]);      \
        acc[(qm)*4+t_][(qn)*2+u_] =                                     \
          mfma16(BV[u_][1], aF[t_][1], acc[(qm)*4+t_][(qn)*2+u_]);      \
      }                                                                 \
    }                                                                   \
    __builtin_amdgcn_s_setprio(0);                                      \
  } while (0)

  f32x4 acc[8][4] = {};
  bf16x8 aF[4][2], bF[2][2], bQ0[2][2];

  // prologue: tile 0 (all 4 halves) + B halves of tile 1; wait tile 0 landed.
  STAGE_A(0, 0); STAGE_A(0, 1); STAGE_B(0, 0); STAGE_B(0, 1);
  STAGE_B(1, 0); STAGE_B(1, 1);
  WVM4();
  BAR();

#pragma unroll 1
  for (int i = 0; i < 8; i++) {
    const int kb = 2 * i + 1;
    // P0: quadrant (0,0) of tile 2i (buf0)
    RDA(0, 0) RDB(bQ0, 0, 0)
    STAGE_A(kb, 0);
    BAR(); WLG();
    MM(0, 0, bQ0);
    BAR();
    // P1: (0,1)
    RDB(bF, 1, 0)
    STAGE_A(kb, 1);
    BAR(); WLG();
    MM(0, 1, bF);
    BAR();
    // P2: (1,1)
    RDA(1, 0)
    if (i < 7) STAGE_B(kb + 1, 0);
    BAR(); WLG();
    MM(1, 1, bF);
    BAR();
    // P3: (1,0); counted vmcnt so tile 2i+1 is readable at P4
    if (i < 7) STAGE_B(kb + 1, 1);
    BAR();
    MM(1, 0, bQ0);
    if (i < 7) { WVM4(); } else { WVM0(); }
    BAR();
    // P4: quadrant (0,0) of tile 2i+1 (buf1)
    RDA(0, 32768) RDB(bQ0, 0, 32768)
    if (i < 7) STAGE_A(kb + 1, 0);
    BAR(); WLG();
    MM(0, 0, bQ0);
    BAR();
    // P5: (0,1)
    RDB(bF, 1, 32768)
    if (i < 7) STAGE_A(kb + 1, 1);
    BAR(); WLG();
    MM(0, 1, bF);
    BAR();
    // P6: (1,1)
    RDA(1, 32768)
    if (i < 7) STAGE_B(kb + 2, 0);
    BAR(); WLG();
    MM(1, 1, bF);
    BAR();
    // P7: (1,0); counted vmcnt so tile 2i+2 is readable at next P0
    if (i < 7) STAGE_B(kb + 2, 1);
    BAR();
    MM(1, 0, bQ0);
    if (i < 7) { WVM4(); }
    BAR();
  }
#undef STAGE_A
#undef STAGE_B
#undef RDA
#undef RDB
#undef MM

  if (sec != 2) {
    const float qs = 0.180336880111120426f;  // 0.125 * log2(e) folded into Q
#pragma unroll
    for (int mi = 0; mi < 8; mi++) {
#pragma unroll
      for (int ni = 0; ni < 4; ni++) {
#pragma unroll
        for (int r = 0; r < 4; r++) {
          float v = acc[mi][ni][r];
          int m = m0 + wm * 128 + mi * 16 + quad * 4 + r;
          int n = n0 + wn * 64 + ni * 16 + l16;
          int ns = n & 1023;
          int h = ns >> 6, e = ns & 63;
          int b = m >> 11, t = m & 2047;
          size_t bh = (size_t)b * 16 + h;
          if (sec == 0) Qb[(bh * 2048 + t) * 64 + e] = f2b(v * qs);
          else          Kb[(bh * 2048 + t) * 64 + e] = f2b(v);
        }
      }
    }
  } else {  // transposed acc: D-row = feature (n side), D-col = token (m side)
#pragma unroll
    for (int mi = 0; mi < 8; mi++) {
#pragma unroll
      for (int ni = 0; ni < 4; ni++) {
#pragma unroll
        for (int r = 0; r < 4; r++) {
          float v = acc[mi][ni][r];
          int n = n0 + wn * 64 + ni * 16 + quad * 4 + r;
          int m = m0 + wm * 128 + mi * 16 + l16;
          int ns = n & 1023;
          int h = ns >> 6, e = ns & 63;
          int b = m >> 11, t = m & 2047;
          size_t bh = (size_t)b * 16 + h;
          Vt[(bh * 64 + e) * 2048 + t] = f2b(v);  // lanes -> consecutive t
        }
      }
    }
  }
}

// ---- flash attention v3: transposed S (A=K, B=Q); per-lane softmax state;
// paired Q-tiles (qb, 15-qb) per block -> uniform 17 j-iters/block.
// grid (bh=64, pair=8), block 512 (8 waves).
// R8: lP stride 40 u16 (period-8 bank walk); setprio around MFMA clusters.
__global__ __launch_bounds__(512, 4) void attn(
    const u16* __restrict__ Q, const u16* __restrict__ K,
    const u16* __restrict__ Vt, u16* __restrict__ O) {
  __shared__ u16 lK[128 * 72];     // [s][e] pad+8
  __shared__ u16 lV[64 * 136];     // [e][s] pad+8
  __shared__ u16 lP[8 * 16 * 40];  // per-wave [16t][32s, stride 40]
  const int tid = threadIdx.x;
  const int lane = tid & 63, wave = tid >> 6;
  const int quad = lane >> 4, l16 = lane & 15;
  const int bh = blockIdx.x;
  const int pidx = blockIdx.y;     // 0..7
  const size_t base = (size_t)bh * (2048 * 64);
  u16* lPw = lP + wave * 640;
  const int b = bh >> 4, h = bh & 15;

  for (int half = 0; half < 2; half++) {
    const int qb = half ? pidx : (15 - pidx);   // long tile first
    const int t0 = qb << 7;
    const int tq = t0 + wave * 16 + l16;
    const bf16x8 qF0 = ldfrag(Q + base + (size_t)tq * 64 + quad * 8);
    const bf16x8 qF1 = ldfrag(Q + base + (size_t)tq * 64 + 32 + quad * 8);
    float m_i = -INFINITY, l_i = 0.f;
    f32x4 o[4] = {};

    for (int j = 0; j <= qb; j++) {
      const int s0 = j << 7;
      __syncthreads();
#pragma unroll
      for (int i = 0; i < 2; i++) {  // stage K tile 128x64
        int c = tid + i * 512;
        int r = c >> 3, col = (c & 7) * 8;
        *(us8*)&lK[r * 72 + col] = *(const us8*)(K + base + (size_t)(s0 + r) * 64 + col);
      }
#pragma unroll
      for (int i = 0; i < 2; i++) {  // stage Vt tile 64x128
        int c = tid + i * 512;
        int e = c >> 4, col = (c & 15) * 8;
        *(us8*)&lV[e * 136 + col] = *(const us8*)(Vt + base + (size_t)e * 2048 + s0 + col);
      }
      __syncthreads();

      // S^T = K·Q^T : lane owns col t=tq, rows s = nt*16+quad*4+r
      f32x4 S[8];
      __builtin_amdgcn_s_setprio(1);
#pragma unroll
      for (int nt = 0; nt < 8; nt++) {
        int sr = nt * 16 + l16;
        f32x4 a = {};
        a = mfma16(ldfrag(&lK[sr * 72 + quad * 8]), qF0, a);
        a = mfma16(ldfrag(&lK[sr * 72 + 32 + quad * 8]), qF1, a);
        S[nt] = a;
      }
      __builtin_amdgcn_s_setprio(0);

      if (j == qb) {  // causal mask on diagonal tile
#pragma unroll
        for (int nt = 0; nt < 8; nt++)
#pragma unroll
          for (int r = 0; r < 4; r++) {
            int s = s0 + nt * 16 + quad * 4 + r;
            if (s > tq) S[nt][r] = -INFINITY;
          }
      }

      // online softmax: in-lane reduce + 2 cross-half shuffles; exp2 direct
      f32x4 m4 = S[0];
#pragma unroll
      for (int nt = 1; nt < 8; nt++)
#pragma unroll
        for (int r = 0; r < 4; r++) m4[r] = fmaxf(m4[r], S[nt][r]);
      float mx = fmaxf(fmaxf(m4[0], m4[1]), fmaxf(m4[2], m4[3]));
      mx = fmaxf(mx, __shfl_xor(mx, 16));
      mx = fmaxf(mx, __shfl_xor(mx, 32));
      float mn = fmaxf(m_i, mx);
      float alpha = __builtin_amdgcn_exp2f(m_i - mn);
      float sum = 0.f;
#pragma unroll
      for (int nt = 0; nt < 8; nt++)
#pragma unroll
        for (int r = 0; r < 4; r++) {
          float p = __builtin_amdgcn_exp2f(S[nt][r] - mn);
          S[nt][r] = p;
          sum += p;
        }
      sum += __shfl_xor(sum, 16);
      sum += __shfl_xor(sum, 32);
      l_i = l_i * alpha + sum;
      m_i = mn;
#pragma unroll
      for (int ot = 0; ot < 4; ot++)
#pragma unroll
        for (int r = 0; r < 4; r++) o[ot][r] *= alpha;

      // PV per 32-wide s-chunk: P^T through wave-private LDS (in-order DS)
#pragma unroll
      for (int c = 0; c < 4; c++) {
        u32x2 d0 = { pkbf(S[2*c][0],   S[2*c][1]),   pkbf(S[2*c][2],   S[2*c][3]) };
        u32x2 d1 = { pkbf(S[2*c+1][0], S[2*c+1][1]), pkbf(S[2*c+1][2], S[2*c+1][3]) };
        *(u32x2*)&lPw[l16 * 40 + quad * 4]      = d0;  // s_local = quad*4+r
        *(u32x2*)&lPw[l16 * 40 + 16 + quad * 4] = d1;  // s_local = 16+quad*4+r
        __asm__ volatile("s_waitcnt lgkmcnt(0)" ::: "memory");
        bf16x8 bP = ldfrag(&lPw[l16 * 40 + quad * 8]);  // B-frag: n=t=l16, k=quad*8+j
        __builtin_amdgcn_s_setprio(1);
#pragma unroll
        for (int ot = 0; ot < 4; ot++)
          o[ot] = mfma16(ldfrag(&lV[(ot * 16 + l16) * 136 + c * 32 + quad * 8]), bP, o[ot]);
        __builtin_amdgcn_s_setprio(0);
      }
    }

    // O^T in C-layout: row e = ot*16+quad*4+r, col t = l16 -> per-lane 8B stores
    const float inv = 1.f / l_i;
#pragma unroll
    for (int ot = 0; ot < 4; ot++) {
      u32x2 pk = { pkbf(o[ot][0] * inv, o[ot][1] * inv),
                   pkbf(o[ot][2] * inv, o[ot][3] * inv) };
      *(u32x2*)&O[((size_t)b * 2048 + tq) * 1024 + h * 64 + ot * 16 + quad * 4] = pk;
    }
  }
}

// ---- GEMM2: out = Ao @ Wo^T + bo, fp32 epilogue. grid (8, 64), block 256.
__global__ __launch_bounds__(256) void gemm_out(
    const u16* __restrict__ A, const u16* __restrict__ W,
    const float* __restrict__ bias, float* __restrict__ out) {
  __shared__ u16 lA[128 * 32];
  __shared__ u16 lB[128 * 32];
  const int tid = threadIdx.x;
  const int lane = tid & 63, wave = tid >> 6;
  const int quad = lane >> 4, l16 = lane & 15;
  const int wr = wave >> 1, wc = wave & 1;
  const int m0 = blockIdx.y * 128;
  const int n0 = blockIdx.x * 128;
  AS3 u16* lA3 = (AS3 u16*)lA;
  AS3 u16* lB3 = (AS3 u16*)lB;
  f32x4 acc[4][4] = {};
  const int swg = (((tid & 3) ^ ((tid >> 3) & 3)) * 8);
  const int qsw = (quad ^ ((l16 >> 1) & 3)) * 8;
  const int ar0 = m0 + (tid >> 2);
  const int br0 = n0 + (tid >> 2);
  const u16* gA0 = A + (size_t)ar0 * 1024 + swg;
  const u16* gA1 = gA0 + 64 * 1024;
  const u16* gB0 = W + (size_t)br0 * 1024 + swg;
  const u16* gB1 = gB0 + 64 * 1024;

  for (int k0 = 0; k0 < 1024; k0 += 32) {
    __syncthreads();
    gl_lds16(gA0 + k0, lA3 + wave * 512);
    gl_lds16(gA1 + k0, lA3 + 2048 + wave * 512);
    gl_lds16(gB0 + k0, lB3 + wave * 512);
    gl_lds16(gB1 + k0, lB3 + 2048 + wave * 512);
    __syncthreads();
    bf16x8 aF[4], bF[4];
#pragma unroll
    for (int mt = 0; mt < 4; mt++)
      aF[mt] = ldfrag(&lA[(wr * 64 + mt * 16 + l16) * 32 + qsw]);
#pragma unroll
    for (int nt = 0; nt < 4; nt++)
      bF[nt] = ldfrag(&lB[(wc * 64 + nt * 16 + l16) * 32 + qsw]);
#pragma unroll
    for (int mt = 0; mt < 4; mt++)
#pragma unroll
      for (int nt = 0; nt < 4; nt++)
        acc[mt][nt] = mfma16(aF[mt], bF[nt], acc[mt][nt]);
  }

#pragma unroll
  for (int mt = 0; mt < 4; mt++) {
#pragma unroll
    for (int nt = 0; nt < 4; nt++) {
#pragma unroll
      for (int r = 0; r < 4; r++) {
        int m = m0 + wr * 64 + mt * 16 + quad * 4 + r;
        int n = n0 + wc * 64 + nt * 16 + l16;
        out[(size_t)m * 1024 + n] = acc[mt][nt][r] + bias[n];
      }
    }
  }
}

extern "C" void kernel_launch(void* const* d_in, const int* in_sizes, int n_in,
                              void* d_out, int out_size, void* d_ws, size_t ws_size,
                              hipStream_t stream) {
  const float* x  = (const float*)d_in[0];
  const float* Wq = (const float*)d_in[1];
  const float* Wk = (const float*)d_in[2];
  const float* Wv = (const float*)d_in[3];
  const float* Wo = (const float*)d_in[4];
  const float* bo = (const float*)d_in[5];
  float* out = (float*)d_out;

  // ws (u16 elems), 40 MB total: xb/Ao | Wqkv | Wob | Qb.
  // d_out doubles as scratch for Kb+Vt (dead before gemm_out's fp32 write).
  u16* ws   = (u16*)d_ws;
  u16* xb   = ws;
  u16* Wqkv = ws + 8388608;
  u16* Wob  = ws + 11534336;
  u16* Qb   = ws + 12582912;
  u16* Ao   = xb;                       // lifetime-disjoint reuse
  u16* Kb   = (u16*)d_out;
  u16* Vt   = Kb + 8388608;

  cvt_all<<<12288, 256, 0, stream>>>(x, Wq, Wk, Wv, Wo, xb, Wqkv, Wob);
  gemm_qkv<<<384, 512, 0, stream>>>(xb, Wqkv, Qb, Kb, Vt);
  attn<<<dim3(64, 8), 512, 0, stream>>>(Qb, Kb, Vt, Ao);
  gemm_out<<<dim3(8, 64), 256, 0, stream>>>(Ao, Wob, bo, out);
}

// Round 3
// 272.952 us; speedup vs baseline: 1.1576x; 1.1576x over previous
//
#include <hip/hip_runtime.h>
#include <cstdint>
#include <cstddef>

// ---- types ----
typedef unsigned short u16;
typedef float  f32x4  __attribute__((ext_vector_type(4)));
typedef __bf16 bf16x8 __attribute__((ext_vector_type(8)));
typedef unsigned short us8 __attribute__((ext_vector_type(8)));
typedef unsigned short us4 __attribute__((ext_vector_type(4)));
typedef float  f32x4v __attribute__((ext_vector_type(4)));
typedef unsigned int u32x2 __attribute__((ext_vector_type(2)));

#define AS1 __attribute__((address_space(1)))
#define AS3 __attribute__((address_space(3)))

// fp32 -> bf16 round-to-nearest-even (scalar)
__device__ __forceinline__ u16 f2b(float f) {
  unsigned u = __float_as_uint(f);
  u += 0x7FFFu + ((u >> 16) & 1u);
  return (u16)(u >> 16);
}

// pack two fp32 -> bf16x2 dword (round-half-up; a = low 16, b = high 16)
__device__ __forceinline__ unsigned pkbf(float a, float b) {
  unsigned ua = __float_as_uint(a) + 0x8000u;
  unsigned ub = __float_as_uint(b) + 0x8000u;
  return __builtin_amdgcn_perm(ub, ua, 0x07060302u);
}

__device__ __forceinline__ bf16x8 ldfrag(const u16* p) {
  us8 v = *(const us8*)p;
  return __builtin_bit_cast(bf16x8, v);
}

__device__ __forceinline__ f32x4 mfma16(bf16x8 a, bf16x8 b, f32x4 c) {
  return __builtin_amdgcn_mfma_f32_16x16x32_bf16(a, b, c, 0, 0, 0);
}

// async global->LDS, 16B per lane; lds base must be wave-uniform (lane*16 auto-added)
__device__ __forceinline__ void gl_lds16(const u16* g, AS3 u16* l) {
  __builtin_amdgcn_global_load_lds((AS1 void*)g, (AS3 void*)l, 16, 0, 0);
}

// XOR-swizzled LDS tile layout (rows of 32 u16 = four 16B granules, 16-row chunks):
//   position(row r, granule g) = r*4 + (g ^ ((r>>1)&3))
// Staging lane L sources granule (L&3)^((L>>3)&3) so position == L (wave-uniform
// base + lane*16 stays legal for global_load_lds). Readers: quad ^ ((l16>>1)&3).
// R6: conflicts 6.29e6 -> 0.

// ---- fused cast: x + all 4 weights, one launch. grid 12288 x 256 ----
__global__ __launch_bounds__(256) void cvt_all(
    const float* __restrict__ x,
    const float* __restrict__ Wq, const float* __restrict__ Wk,
    const float* __restrict__ Wv, const float* __restrict__ Wo,
    u16* __restrict__ xb, u16* __restrict__ Wqkv, u16* __restrict__ Wob) {
  int blk = blockIdx.x;
  const float* s;
  u16* d;
  int i;
  if (blk < 8192)       { s = x;  d = xb;             i = blk * 256 + threadIdx.x; }
  else if (blk < 9216)  { s = Wq; d = Wqkv;           i = (blk - 8192) * 256 + threadIdx.x; }
  else if (blk < 10240) { s = Wk; d = Wqkv + 1048576; i = (blk - 9216) * 256 + threadIdx.x; }
  else if (blk < 11264) { s = Wv; d = Wqkv + 2097152; i = (blk - 10240) * 256 + threadIdx.x; }
  else                  { s = Wo; d = Wob;            i = (blk - 11264) * 256 + threadIdx.x; }
  f32x4v f = ((const f32x4v*)s)[i];
  us4 o = { f2b(f[0]), f2b(f[1]), f2b(f[2]), f2b(f[3]) };
  ((us4*)d)[i] = o;
}

// ---- GEMM1: C = X @ Wqkv^T -> Q (prescaled by 0.125*log2e), K, Vt.
// R10: reverted to the R1 m97 configuration (measured 77.6 us / 664 TF here).
// The R9 8-phase 256^2 port regressed to 133 us: 384 blocks @ 1 block/CU = 1.5
// dispatch rounds, 8-wave lockstep barriers with no co-resident block to
// de-correlate (m114), and per-XCD L2 thrash (B 6MB > 4MB L2). 128x128 tile,
// 256 threads, BK=32, 2-barrier loop, 3 blocks/CU. grid (24, 64).
__global__ __launch_bounds__(256) void gemm_qkv(
    const u16* __restrict__ A, const u16* __restrict__ W,
    u16* __restrict__ Qb, u16* __restrict__ Kb, u16* __restrict__ Vt) {
  __shared__ u16 lA[128 * 32];   // 8 KB
  __shared__ u16 lB[128 * 32];   // 8 KB
  const int tid = threadIdx.x;
  const int lane = tid & 63, wave = tid >> 6;
  const int quad = lane >> 4, l16 = lane & 15;
  const int wr = wave >> 1, wc = wave & 1;
  const int m0 = blockIdx.y * 128;
  const int n0 = blockIdx.x * 128;
  const int sec = n0 >> 10;  // 0=Q 1=K 2=V
  AS3 u16* lA3 = (AS3 u16*)lA;
  AS3 u16* lB3 = (AS3 u16*)lB;
  f32x4 acc[4][4] = {};
  const int swg = (((tid & 3) ^ ((tid >> 3) & 3)) * 8);  // staging source granule
  const int qsw = (quad ^ ((l16 >> 1) & 3)) * 8;         // reader granule
  const int ar0 = m0 + (tid >> 2);          // rows 0..63 (+64 for second inst)
  const int br0 = n0 + (tid >> 2);

  const u16* gA0 = A + (size_t)ar0 * 1024 + swg;
  const u16* gA1 = gA0 + 64 * 1024;
  const u16* gB0 = W + (size_t)br0 * 1024 + swg;
  const u16* gB1 = gB0 + 64 * 1024;

  for (int k0 = 0; k0 < 1024; k0 += 32) {
    __syncthreads();
    gl_lds16(gA0 + k0, lA3 + wave * 512);
    gl_lds16(gA1 + k0, lA3 + 2048 + wave * 512);
    gl_lds16(gB0 + k0, lB3 + wave * 512);
    gl_lds16(gB1 + k0, lB3 + 2048 + wave * 512);
    __syncthreads();
    bf16x8 aF[4], bF[4];
#pragma unroll
    for (int mt = 0; mt < 4; mt++)
      aF[mt] = ldfrag(&lA[(wr * 64 + mt * 16 + l16) * 32 + qsw]);
#pragma unroll
    for (int nt = 0; nt < 4; nt++)
      bF[nt] = ldfrag(&lB[(wc * 64 + nt * 16 + l16) * 32 + qsw]);
    if (sec != 2) {
#pragma unroll
      for (int mt = 0; mt < 4; mt++)
#pragma unroll
        for (int nt = 0; nt < 4; nt++)
          acc[mt][nt] = mfma16(aF[mt], bF[nt], acc[mt][nt]);
    } else {  // transposed accumulate: C[n][m]
#pragma unroll
      for (int mt = 0; mt < 4; mt++)
#pragma unroll
        for (int nt = 0; nt < 4; nt++)
          acc[mt][nt] = mfma16(bF[nt], aF[mt], acc[mt][nt]);
    }
  }

  if (sec != 2) {
    const float qs = 0.180336880111120426f;  // 0.125 * log2(e) folded into Q
#pragma unroll
    for (int mt = 0; mt < 4; mt++) {
#pragma unroll
      for (int nt = 0; nt < 4; nt++) {
#pragma unroll
        for (int r = 0; r < 4; r++) {
          float v = acc[mt][nt][r];
          int m = m0 + wr * 64 + mt * 16 + quad * 4 + r;
          int n = n0 + wc * 64 + nt * 16 + l16;
          int ns = n & 1023;
          int h = ns >> 6, e = ns & 63;
          int b = m >> 11, t = m & 2047;
          size_t bh = (size_t)b * 16 + h;
          if (sec == 0) Qb[(bh * 2048 + t) * 64 + e] = f2b(v * qs);
          else          Kb[(bh * 2048 + t) * 64 + e] = f2b(v);
        }
      }
    }
  } else {
#pragma unroll
    for (int mt = 0; mt < 4; mt++) {
#pragma unroll
      for (int nt = 0; nt < 4; nt++) {
#pragma unroll
        for (int r = 0; r < 4; r++) {
          float v = acc[mt][nt][r];
          int n = n0 + wc * 64 + nt * 16 + quad * 4 + r;  // feature (row of C)
          int m = m0 + wr * 64 + mt * 16 + l16;           // token (col of C)
          int ns = n & 1023;
          int h = ns >> 6, e = ns & 63;
          int b = m >> 11, t = m & 2047;
          size_t bh = (size_t)b * 16 + h;
          Vt[(bh * 64 + e) * 2048 + t] = f2b(v);          // lanes -> consecutive t
        }
      }
    }
  }
}

// ---- flash attention v3: transposed S (A=K, B=Q); per-lane softmax state;
// paired Q-tiles (qb, 15-qb) per block -> uniform 17 j-iters/block.
// grid (bh=64, pair=8), block 512 (8 waves).
// R8: lP stride 40 u16 (period-8 bank walk); setprio around MFMA clusters.
// R10: T14 async-STAGE split — next K/V tile global-loaded into regs during
// current tile's compute; raw s_barrier + counted waits (no __syncthreads,
// which would drain the prefetch). lgkmcnt(0) between ds_write and reg reuse.
__global__ __launch_bounds__(512, 4) void attn(
    const u16* __restrict__ Q, const u16* __restrict__ K,
    const u16* __restrict__ Vt, u16* __restrict__ O) {
  __shared__ u16 lK[128 * 72];     // [s][e] pad+8
  __shared__ u16 lV[64 * 136];     // [e][s] pad+8
  __shared__ u16 lP[8 * 16 * 40];  // per-wave [16t][32s, stride 40]
  const int tid = threadIdx.x;
  const int lane = tid & 63, wave = tid >> 6;
  const int quad = lane >> 4, l16 = lane & 15;
  const int bh = blockIdx.x;
  const int pidx = blockIdx.y;     // 0..7
  const size_t base = (size_t)bh * (2048 * 64);
  u16* lPw = lP + wave * 640;
  const int b = bh >> 4, h = bh & 15;

  // T14 staging addresses (per-thread constants; tile offset added per j)
  const int c1 = tid + 512;
  const int rK0 = tid >> 3, cK0 = (tid & 7) * 8;
  const int rK1 = c1 >> 3,  cK1 = (c1 & 7) * 8;
  const int eV0 = tid >> 4, cV0 = (tid & 15) * 8;
  const int eV1 = c1 >> 4,  cV1 = (c1 & 15) * 8;
  const u16* gK0 = K + base + (size_t)rK0 * 64 + cK0;
  const u16* gK1 = K + base + (size_t)rK1 * 64 + cK1;
  const u16* gV0 = Vt + base + (size_t)eV0 * 2048 + cV0;
  const u16* gV1 = Vt + base + (size_t)eV1 * 2048 + cV1;
  u16* dK0 = &lK[rK0 * 72 + cK0];
  u16* dK1 = &lK[rK1 * 72 + cK1];
  u16* dV0 = &lV[eV0 * 136 + cV0];
  u16* dV1 = &lV[eV1 * 136 + cV1];

  for (int half = 0; half < 2; half++) {
    const int qb = half ? pidx : (15 - pidx);   // long tile first
    const int t0 = qb << 7;
    const int tq = t0 + wave * 16 + l16;
    const bf16x8 qF0 = ldfrag(Q + base + (size_t)tq * 64 + quad * 8);
    const bf16x8 qF1 = ldfrag(Q + base + (size_t)tq * 64 + 32 + quad * 8);
    float m_i = -INFINITY, l_i = 0.f;
    f32x4 o[4] = {};

    // prefetch tile j=0 into regs (touches no LDS; safe pre-barrier)
    us8 sK0 = *(const us8*)gK0;
    us8 sK1 = *(const us8*)gK1;
    us8 sV0 = *(const us8*)gV0;
    us8 sV1 = *(const us8*)gV1;

    for (int j = 0; j <= qb; j++) {
      const int s0 = j << 7;
      __builtin_amdgcn_s_barrier();                 // all waves done reading prev tiles
      __builtin_amdgcn_sched_barrier(0);
      __asm__ volatile("s_waitcnt vmcnt(0)" ::: "memory");  // prefetch landed
      __builtin_amdgcn_sched_barrier(0);
      *(us8*)dK0 = sK0;  *(us8*)dK1 = sK1;          // publish tile j
      *(us8*)dV0 = sV0;  *(us8*)dV1 = sV1;
      __asm__ volatile("s_waitcnt lgkmcnt(0)" ::: "memory");  // ds_writes done -> regs reusable
      __builtin_amdgcn_sched_barrier(0);
      __builtin_amdgcn_s_barrier();                 // tiles visible to all waves
      __builtin_amdgcn_sched_barrier(0);
      if (j < qb) {                                 // issue tile j+1; hides under compute
        const int sn = (j + 1) << 7;
        sK0 = *(const us8*)(gK0 + (size_t)sn * 64);
        sK1 = *(const us8*)(gK1 + (size_t)sn * 64);
        sV0 = *(const us8*)(gV0 + sn);
        sV1 = *(const us8*)(gV1 + sn);
      }

      // S^T = K·Q^T : lane owns col t=tq, rows s = nt*16+quad*4+r
      f32x4 S[8];
      __builtin_amdgcn_s_setprio(1);
#pragma unroll
      for (int nt = 0; nt < 8; nt++) {
        int sr = nt * 16 + l16;
        f32x4 a = {};
        a = mfma16(ldfrag(&lK[sr * 72 + quad * 8]), qF0, a);
        a = mfma16(ldfrag(&lK[sr * 72 + 32 + quad * 8]), qF1, a);
        S[nt] = a;
      }
      __builtin_amdgcn_s_setprio(0);

      if (j == qb) {  // causal mask on diagonal tile
#pragma unroll
        for (int nt = 0; nt < 8; nt++)
#pragma unroll
          for (int r = 0; r < 4; r++) {
            int s = s0 + nt * 16 + quad * 4 + r;
            if (s > tq) S[nt][r] = -INFINITY;
          }
      }

      // online softmax: in-lane reduce + 2 cross-half shuffles; exp2 direct
      f32x4 m4 = S[0];
#pragma unroll
      for (int nt = 1; nt < 8; nt++)
#pragma unroll
        for (int r = 0; r < 4; r++) m4[r] = fmaxf(m4[r], S[nt][r]);
      float mx = fmaxf(fmaxf(m4[0], m4[1]), fmaxf(m4[2], m4[3]));
      mx = fmaxf(mx, __shfl_xor(mx, 16));
      mx = fmaxf(mx, __shfl_xor(mx, 32));
      float mn = fmaxf(m_i, mx);
      float alpha = __builtin_amdgcn_exp2f(m_i - mn);
      float sum = 0.f;
#pragma unroll
      for (int nt = 0; nt < 8; nt++)
#pragma unroll
        for (int r = 0; r < 4; r++) {
          float p = __builtin_amdgcn_exp2f(S[nt][r] - mn);
          S[nt][r] = p;
          sum += p;
        }
      sum += __shfl_xor(sum, 16);
      sum += __shfl_xor(sum, 32);
      l_i = l_i * alpha + sum;
      m_i = mn;
#pragma unroll
      for (int ot = 0; ot < 4; ot++)
#pragma unroll
        for (int r = 0; r < 4; r++) o[ot][r] *= alpha;

      // PV per 32-wide s-chunk: P^T through wave-private LDS (in-order DS)
#pragma unroll
      for (int c = 0; c < 4; c++) {
        u32x2 d0 = { pkbf(S[2*c][0],   S[2*c][1]),   pkbf(S[2*c][2],   S[2*c][3]) };
        u32x2 d1 = { pkbf(S[2*c+1][0], S[2*c+1][1]), pkbf(S[2*c+1][2], S[2*c+1][3]) };
        *(u32x2*)&lPw[l16 * 40 + quad * 4]      = d0;  // s_local = quad*4+r
        *(u32x2*)&lPw[l16 * 40 + 16 + quad * 4] = d1;  // s_local = 16+quad*4+r
        __asm__ volatile("s_waitcnt lgkmcnt(0)" ::: "memory");
        bf16x8 bP = ldfrag(&lPw[l16 * 40 + quad * 8]);  // B-frag: n=t=l16, k=quad*8+j
        __builtin_amdgcn_s_setprio(1);
#pragma unroll
        for (int ot = 0; ot < 4; ot++)
          o[ot] = mfma16(ldfrag(&lV[(ot * 16 + l16) * 136 + c * 32 + quad * 8]), bP, o[ot]);
        __builtin_amdgcn_s_setprio(0);
      }
    }

    // O^T in C-layout: row e = ot*16+quad*4+r, col t = l16 -> per-lane 8B stores
    const float inv = 1.f / l_i;
#pragma unroll
    for (int ot = 0; ot < 4; ot++) {
      u32x2 pk = { pkbf(o[ot][0] * inv, o[ot][1] * inv),
                   pkbf(o[ot][2] * inv, o[ot][3] * inv) };
      *(u32x2*)&O[((size_t)b * 2048 + tq) * 1024 + h * 64 + ot * 16 + quad * 4] = pk;
    }
  }
}

// ---- GEMM2: out = Ao @ Wo^T + bo, fp32 epilogue. grid (8, 64), block 256.
__global__ __launch_bounds__(256) void gemm_out(
    const u16* __restrict__ A, const u16* __restrict__ W,
    const float* __restrict__ bias, float* __restrict__ out) {
  __shared__ u16 lA[128 * 32];
  __shared__ u16 lB[128 * 32];
  const int tid = threadIdx.x;
  const int lane = tid & 63, wave = tid >> 6;
  const int quad = lane >> 4, l16 = lane & 15;
  const int wr = wave >> 1, wc = wave & 1;
  const int m0 = blockIdx.y * 128;
  const int n0 = blockIdx.x * 128;
  AS3 u16* lA3 = (AS3 u16*)lA;
  AS3 u16* lB3 = (AS3 u16*)lB;
  f32x4 acc[4][4] = {};
  const int swg = (((tid & 3) ^ ((tid >> 3) & 3)) * 8);
  const int qsw = (quad ^ ((l16 >> 1) & 3)) * 8;
  const int ar0 = m0 + (tid >> 2);
  const int br0 = n0 + (tid >> 2);
  const u16* gA0 = A + (size_t)ar0 * 1024 + swg;
  const u16* gA1 = gA0 + 64 * 1024;
  const u16* gB0 = W + (size_t)br0 * 1024 + swg;
  const u16* gB1 = gB0 + 64 * 1024;

  for (int k0 = 0; k0 < 1024; k0 += 32) {
    __syncthreads();
    gl_lds16(gA0 + k0, lA3 + wave * 512);
    gl_lds16(gA1 + k0, lA3 + 2048 + wave * 512);
    gl_lds16(gB0 + k0, lB3 + wave * 512);
    gl_lds16(gB1 + k0, lB3 + 2048 + wave * 512);
    __syncthreads();
    bf16x8 aF[4], bF[4];
#pragma unroll
    for (int mt = 0; mt < 4; mt++)
      aF[mt] = ldfrag(&lA[(wr * 64 + mt * 16 + l16) * 32 + qsw]);
#pragma unroll
    for (int nt = 0; nt < 4; nt++)
      bF[nt] = ldfrag(&lB[(wc * 64 + nt * 16 + l16) * 32 + qsw]);
#pragma unroll
    for (int mt = 0; mt < 4; mt++)
#pragma unroll
      for (int nt = 0; nt < 4; nt++)
        acc[mt][nt] = mfma16(aF[mt], bF[nt], acc[mt][nt]);
  }

#pragma unroll
  for (int mt = 0; mt < 4; mt++) {
#pragma unroll
    for (int nt = 0; nt < 4; nt++) {
#pragma unroll
      for (int r = 0; r < 4; r++) {
        int m = m0 + wr * 64 + mt * 16 + quad * 4 + r;
        int n = n0 + wc * 64 + nt * 16 + l16;
        out[(size_t)m * 1024 + n] = acc[mt][nt][r] + bias[n];
      }
    }
  }
}

extern "C" void kernel_launch(void* const* d_in, const int* in_sizes, int n_in,
                              void* d_out, int out_size, void* d_ws, size_t ws_size,
                              hipStream_t stream) {
  const float* x  = (const float*)d_in[0];
  const float* Wq = (const float*)d_in[1];
  const float* Wk = (const float*)d_in[2];
  const float* Wv = (const float*)d_in[3];
  const float* Wo = (const float*)d_in[4];
  const float* bo = (const float*)d_in[5];
  float* out = (float*)d_out;

  // ws (u16 elems), 40 MB total: xb/Ao | Wqkv | Wob | Qb.
  // d_out doubles as scratch for Kb+Vt (dead before gemm_out's fp32 write).
  u16* ws   = (u16*)d_ws;
  u16* xb   = ws;
  u16* Wqkv = ws + 8388608;
  u16* Wob  = ws + 11534336;
  u16* Qb   = ws + 12582912;
  u16* Ao   = xb;                       // lifetime-disjoint reuse
  u16* Kb   = (u16*)d_out;
  u16* Vt   = Kb + 8388608;

  cvt_all<<<12288, 256, 0, stream>>>(x, Wq, Wk, Wv, Wo, xb, Wqkv, Wob);
  gemm_qkv<<<dim3(24, 64), 256, 0, stream>>>(xb, Wqkv, Qb, Kb, Vt);
  attn<<<dim3(64, 8), 512, 0, stream>>>(Qb, Kb, Vt, Ao);
  gemm_out<<<dim3(8, 64), 256, 0, stream>>>(Ao, Wob, bo, out);
}

// Round 4
// 258.016 us; speedup vs baseline: 1.2246x; 1.0579x over previous
//
#include <hip/hip_runtime.h>
#include <cstdint>
#include <cstddef>

// ---- types ----
typedef unsigned short u16;
typedef float  f32x4  __attribute__((ext_vector_type(4)));
typedef __bf16 bf16x8 __attribute__((ext_vector_type(8)));
typedef unsigned short us8 __attribute__((ext_vector_type(8)));
typedef unsigned short us4 __attribute__((ext_vector_type(4)));
typedef float  f32x4v __attribute__((ext_vector_type(4)));
typedef unsigned int u32x2 __attribute__((ext_vector_type(2)));

#define AS1 __attribute__((address_space(1)))
#define AS3 __attribute__((address_space(3)))

// fp32 -> bf16 round-to-nearest-even (scalar)
__device__ __forceinline__ u16 f2b(float f) {
  unsigned u = __float_as_uint(f);
  u += 0x7FFFu + ((u >> 16) & 1u);
  return (u16)(u >> 16);
}

// pack two fp32 -> bf16x2 dword (round-half-up; a = low 16, b = high 16)
__device__ __forceinline__ unsigned pkbf(float a, float b) {
  unsigned ua = __float_as_uint(a) + 0x8000u;
  unsigned ub = __float_as_uint(b) + 0x8000u;
  return __builtin_amdgcn_perm(ub, ua, 0x07060302u);
}

__device__ __forceinline__ bf16x8 ldfrag(const u16* p) {
  us8 v = *(const us8*)p;
  return __builtin_bit_cast(bf16x8, v);
}

__device__ __forceinline__ f32x4 mfma16(bf16x8 a, bf16x8 b, f32x4 c) {
  return __builtin_amdgcn_mfma_f32_16x16x32_bf16(a, b, c, 0, 0, 0);
}

// async global->LDS, 16B per lane; lds base must be wave-uniform (lane*16 auto-added)
__device__ __forceinline__ void gl_lds16(const u16* g, AS3 u16* l) {
  __builtin_amdgcn_global_load_lds((AS1 void*)g, (AS3 void*)l, 16, 0, 0);
}

// XOR-swizzled LDS tile layout (rows of 32 u16 = four 16B granules, 16-row chunks):
//   position(row r, granule g) = r*4 + (g ^ ((r>>1)&3))
// Staging lane L sources granule (L&3)^((L>>3)&3) so position == L (wave-uniform
// base + lane*16 stays legal for global_load_lds). Readers: quad ^ ((l16>>1)&3).
// R6: conflicts 6.29e6 -> 0.

// ---- fused cast: x + all 4 weights, one launch. grid 12288 x 256 ----
__global__ __launch_bounds__(256) void cvt_all(
    const float* __restrict__ x,
    const float* __restrict__ Wq, const float* __restrict__ Wk,
    const float* __restrict__ Wv, const float* __restrict__ Wo,
    u16* __restrict__ xb, u16* __restrict__ Wqkv, u16* __restrict__ Wob) {
  int blk = blockIdx.x;
  const float* s;
  u16* d;
  int i;
  if (blk < 8192)       { s = x;  d = xb;             i = blk * 256 + threadIdx.x; }
  else if (blk < 9216)  { s = Wq; d = Wqkv;           i = (blk - 8192) * 256 + threadIdx.x; }
  else if (blk < 10240) { s = Wk; d = Wqkv + 1048576; i = (blk - 9216) * 256 + threadIdx.x; }
  else if (blk < 11264) { s = Wv; d = Wqkv + 2097152; i = (blk - 10240) * 256 + threadIdx.x; }
  else                  { s = Wo; d = Wob;            i = (blk - 11264) * 256 + threadIdx.x; }
  f32x4v f = ((const f32x4v*)s)[i];
  us4 o = { f2b(f[0]), f2b(f[1]), f2b(f[2]), f2b(f[3]) };
  ((us4*)d)[i] = o;
}

// ---- GEMM1: C = X @ Wqkv^T -> Q (prescaled by 0.125*log2e), K, Vt.
// m97 configuration (664 TF measured here): 128x128 tile, 256 threads, BK=32,
// 2-barrier loop, 3 blocks/CU (12 independent waves/CU de-correlate barrier
// stalls — m114). R9's 8-phase 256^2 port regressed (grid imbalance + L2
// thrash); keep this. grid (24, 64).
__global__ __launch_bounds__(256) void gemm_qkv(
    const u16* __restrict__ A, const u16* __restrict__ W,
    u16* __restrict__ Qb, u16* __restrict__ Kb, u16* __restrict__ Vt) {
  __shared__ u16 lA[128 * 32];   // 8 KB
  __shared__ u16 lB[128 * 32];   // 8 KB
  const int tid = threadIdx.x;
  const int lane = tid & 63, wave = tid >> 6;
  const int quad = lane >> 4, l16 = lane & 15;
  const int wr = wave >> 1, wc = wave & 1;
  const int m0 = blockIdx.y * 128;
  const int n0 = blockIdx.x * 128;
  const int sec = n0 >> 10;  // 0=Q 1=K 2=V
  AS3 u16* lA3 = (AS3 u16*)lA;
  AS3 u16* lB3 = (AS3 u16*)lB;
  f32x4 acc[4][4] = {};
  const int swg = (((tid & 3) ^ ((tid >> 3) & 3)) * 8);  // staging source granule
  const int qsw = (quad ^ ((l16 >> 1) & 3)) * 8;         // reader granule
  const int ar0 = m0 + (tid >> 2);          // rows 0..63 (+64 for second inst)
  const int br0 = n0 + (tid >> 2);

  const u16* gA0 = A + (size_t)ar0 * 1024 + swg;
  const u16* gA1 = gA0 + 64 * 1024;
  const u16* gB0 = W + (size_t)br0 * 1024 + swg;
  const u16* gB1 = gB0 + 64 * 1024;

  for (int k0 = 0; k0 < 1024; k0 += 32) {
    __syncthreads();
    gl_lds16(gA0 + k0, lA3 + wave * 512);
    gl_lds16(gA1 + k0, lA3 + 2048 + wave * 512);
    gl_lds16(gB0 + k0, lB3 + wave * 512);
    gl_lds16(gB1 + k0, lB3 + 2048 + wave * 512);
    __syncthreads();
    bf16x8 aF[4], bF[4];
#pragma unroll
    for (int mt = 0; mt < 4; mt++)
      aF[mt] = ldfrag(&lA[(wr * 64 + mt * 16 + l16) * 32 + qsw]);
#pragma unroll
    for (int nt = 0; nt < 4; nt++)
      bF[nt] = ldfrag(&lB[(wc * 64 + nt * 16 + l16) * 32 + qsw]);
    if (sec != 2) {
#pragma unroll
      for (int mt = 0; mt < 4; mt++)
#pragma unroll
        for (int nt = 0; nt < 4; nt++)
          acc[mt][nt] = mfma16(aF[mt], bF[nt], acc[mt][nt]);
    } else {  // transposed accumulate: C[n][m]
#pragma unroll
      for (int mt = 0; mt < 4; mt++)
#pragma unroll
        for (int nt = 0; nt < 4; nt++)
          acc[mt][nt] = mfma16(bF[nt], aF[mt], acc[mt][nt]);
    }
  }

  if (sec != 2) {
    const float qs = 0.180336880111120426f;  // 0.125 * log2(e) folded into Q
#pragma unroll
    for (int mt = 0; mt < 4; mt++) {
#pragma unroll
      for (int nt = 0; nt < 4; nt++) {
#pragma unroll
        for (int r = 0; r < 4; r++) {
          float v = acc[mt][nt][r];
          int m = m0 + wr * 64 + mt * 16 + quad * 4 + r;
          int n = n0 + wc * 64 + nt * 16 + l16;
          int ns = n & 1023;
          int h = ns >> 6, e = ns & 63;
          int b = m >> 11, t = m & 2047;
          size_t bh = (size_t)b * 16 + h;
          if (sec == 0) Qb[(bh * 2048 + t) * 64 + e] = f2b(v * qs);
          else          Kb[(bh * 2048 + t) * 64 + e] = f2b(v);
        }
      }
    }
  } else {
#pragma unroll
    for (int mt = 0; mt < 4; mt++) {
#pragma unroll
      for (int nt = 0; nt < 4; nt++) {
#pragma unroll
        for (int r = 0; r < 4; r++) {
          float v = acc[mt][nt][r];
          int n = n0 + wc * 64 + nt * 16 + quad * 4 + r;  // feature (row of C)
          int m = m0 + wr * 64 + mt * 16 + l16;           // token (col of C)
          int ns = n & 1023;
          int h = ns >> 6, e = ns & 63;
          int b = m >> 11, t = m & 2047;
          size_t bh = (size_t)b * 16 + h;
          Vt[(bh * 64 + e) * 2048 + t] = f2b(v);          // lanes -> consecutive t
        }
      }
    }
  }
}

// ---- flash attention v3: transposed S (A=K, B=Q); per-lane softmax state;
// paired Q-tiles (qb, 15-qb) per block -> uniform 17 j-iters/block.
// grid (bh=64, pair=8), block 512 (8 waves).
// R8: lP stride 40 u16 (period-8 bank walk); setprio around MFMA clusters.
// R11: T14 reverted (regressed: TLP already hid staging latency; FETCH +11MB).
// New: (1) l-sum via ones-MFMA — 4 extra MFMA/iter on the idle matrix pipe
// replace 32 v_add + 2 shfl; l now sums the same bf16-rounded P the PV
// numerator uses (consistent weights). (2) T13 defer-max THR=8: wave-uniform
// skip of alpha-exp2 + 16-mul O-rescale when the tile max doesn't grow.
__global__ __launch_bounds__(512, 4) void attn(
    const u16* __restrict__ Q, const u16* __restrict__ K,
    const u16* __restrict__ Vt, u16* __restrict__ O) {
  __shared__ u16 lK[128 * 72];     // [s][e] pad+8
  __shared__ u16 lV[64 * 136];     // [e][s] pad+8
  __shared__ u16 lP[8 * 16 * 40];  // per-wave [16t][32s, stride 40]
  const int tid = threadIdx.x;
  const int lane = tid & 63, wave = tid >> 6;
  const int quad = lane >> 4, l16 = lane & 15;
  const int bh = blockIdx.x;
  const int pidx = blockIdx.y;     // 0..7
  const size_t base = (size_t)bh * (2048 * 64);
  u16* lPw = lP + wave * 640;
  const int b = bh >> 4, h = bh & 15;

  // ones A-frag for the l-sum MFMA (bf16 1.0 = 0x3F80)
  us8 ones_u = { 0x3F80, 0x3F80, 0x3F80, 0x3F80, 0x3F80, 0x3F80, 0x3F80, 0x3F80 };
  const bf16x8 onesA = __builtin_bit_cast(bf16x8, ones_u);

  for (int half = 0; half < 2; half++) {
    const int qb = half ? pidx : (15 - pidx);   // long tile first
    const int t0 = qb << 7;
    const int tq = t0 + wave * 16 + l16;
    const bf16x8 qF0 = ldfrag(Q + base + (size_t)tq * 64 + quad * 8);
    const bf16x8 qF1 = ldfrag(Q + base + (size_t)tq * 64 + 32 + quad * 8);
    float m_i = -INFINITY, l_i = 0.f;
    f32x4 o[4] = {};

    for (int j = 0; j <= qb; j++) {
      const int s0 = j << 7;
      __syncthreads();
#pragma unroll
      for (int i = 0; i < 2; i++) {  // stage K tile 128x64
        int c = tid + i * 512;
        int r = c >> 3, col = (c & 7) * 8;
        *(us8*)&lK[r * 72 + col] = *(const us8*)(K + base + (size_t)(s0 + r) * 64 + col);
      }
#pragma unroll
      for (int i = 0; i < 2; i++) {  // stage Vt tile 64x128
        int c = tid + i * 512;
        int e = c >> 4, col = (c & 15) * 8;
        *(us8*)&lV[e * 136 + col] = *(const us8*)(Vt + base + (size_t)e * 2048 + s0 + col);
      }
      __syncthreads();

      // S^T = K·Q^T : lane owns col t=tq, rows s = nt*16+quad*4+r
      f32x4 S[8];
      __builtin_amdgcn_s_setprio(1);
#pragma unroll
      for (int nt = 0; nt < 8; nt++) {
        int sr = nt * 16 + l16;
        f32x4 a = {};
        a = mfma16(ldfrag(&lK[sr * 72 + quad * 8]), qF0, a);
        a = mfma16(ldfrag(&lK[sr * 72 + 32 + quad * 8]), qF1, a);
        S[nt] = a;
      }
      __builtin_amdgcn_s_setprio(0);

      if (j == qb) {  // causal mask on diagonal tile
#pragma unroll
        for (int nt = 0; nt < 8; nt++)
#pragma unroll
          for (int r = 0; r < 4; r++) {
            int s = s0 + nt * 16 + quad * 4 + r;
            if (s > tq) S[nt][r] = -INFINITY;
          }
      }

      // online softmax: in-lane max reduce + 2 cross-half shuffles
      f32x4 m4 = S[0];
#pragma unroll
      for (int nt = 1; nt < 8; nt++)
#pragma unroll
        for (int r = 0; r < 4; r++) m4[r] = fmaxf(m4[r], S[nt][r]);
      float mx = fmaxf(fmaxf(m4[0], m4[1]), fmaxf(m4[2], m4[3]));
      mx = fmaxf(mx, __shfl_xor(mx, 16));
      mx = fmaxf(mx, __shfl_xor(mx, 32));
      // T13 defer-max: skip rescale when no lane's tile-max grew past m_i+8.
      // P then bounded by 2^8; fp32 o/l accumulators tolerate; first iter
      // (m_i=-inf) always takes the full path.
      if (!__all(mx <= m_i + 8.0f)) {
        float mn = fmaxf(m_i, mx);
        float alpha = __builtin_amdgcn_exp2f(m_i - mn);
#pragma unroll
        for (int ot = 0; ot < 4; ot++)
#pragma unroll
          for (int r = 0; r < 4; r++) o[ot][r] *= alpha;
        l_i *= alpha;
        m_i = mn;
      }
#pragma unroll
      for (int nt = 0; nt < 8; nt++)
#pragma unroll
        for (int r = 0; r < 4; r++)
          S[nt][r] = __builtin_amdgcn_exp2f(S[nt][r] - m_i);

      // PV per 32-wide s-chunk: P^T through wave-private LDS (in-order DS).
      // l-sum rides the MFMA pipe: ol = onesA · bP accumulated per chunk
      // (all 16 D-rows identical = chunk column-sum for t=l16).
      f32x4 ol = {};
#pragma unroll
      for (int c = 0; c < 4; c++) {
        u32x2 d0 = { pkbf(S[2*c][0],   S[2*c][1]),   pkbf(S[2*c][2],   S[2*c][3]) };
        u32x2 d1 = { pkbf(S[2*c+1][0], S[2*c+1][1]), pkbf(S[2*c+1][2], S[2*c+1][3]) };
        *(u32x2*)&lPw[l16 * 40 + quad * 4]      = d0;  // s_local = quad*4+r
        *(u32x2*)&lPw[l16 * 40 + 16 + quad * 4] = d1;  // s_local = 16+quad*4+r
        __asm__ volatile("s_waitcnt lgkmcnt(0)" ::: "memory");
        bf16x8 bP = ldfrag(&lPw[l16 * 40 + quad * 8]);  // B-frag: n=t=l16, k=quad*8+j
        __builtin_amdgcn_s_setprio(1);
#pragma unroll
        for (int ot = 0; ot < 4; ot++)
          o[ot] = mfma16(ldfrag(&lV[(ot * 16 + l16) * 136 + c * 32 + quad * 8]), bP, o[ot]);
        ol = mfma16(onesA, bP, ol);
        __builtin_amdgcn_s_setprio(0);
      }
      l_i += ol[0];
    }

    // O^T in C-layout: row e = ot*16+quad*4+r, col t = l16 -> per-lane 8B stores
    const float inv = 1.f / l_i;
#pragma unroll
    for (int ot = 0; ot < 4; ot++) {
      u32x2 pk = { pkbf(o[ot][0] * inv, o[ot][1] * inv),
                   pkbf(o[ot][2] * inv, o[ot][3] * inv) };
      *(u32x2*)&O[((size_t)b * 2048 + tq) * 1024 + h * 64 + ot * 16 + quad * 4] = pk;
    }
  }
}

// ---- GEMM2: out = Ao @ Wo^T + bo, fp32 epilogue. grid (8, 64), block 256.
__global__ __launch_bounds__(256) void gemm_out(
    const u16* __restrict__ A, const u16* __restrict__ W,
    const float* __restrict__ bias, float* __restrict__ out) {
  __shared__ u16 lA[128 * 32];
  __shared__ u16 lB[128 * 32];
  const int tid = threadIdx.x;
  const int lane = tid & 63, wave = tid >> 6;
  const int quad = lane >> 4, l16 = lane & 15;
  const int wr = wave >> 1, wc = wave & 1;
  const int m0 = blockIdx.y * 128;
  const int n0 = blockIdx.x * 128;
  AS3 u16* lA3 = (AS3 u16*)lA;
  AS3 u16* lB3 = (AS3 u16*)lB;
  f32x4 acc[4][4] = {};
  const int swg = (((tid & 3) ^ ((tid >> 3) & 3)) * 8);
  const int qsw = (quad ^ ((l16 >> 1) & 3)) * 8;
  const int ar0 = m0 + (tid >> 2);
  const int br0 = n0 + (tid >> 2);
  const u16* gA0 = A + (size_t)ar0 * 1024 + swg;
  const u16* gA1 = gA0 + 64 * 1024;
  const u16* gB0 = W + (size_t)br0 * 1024 + swg;
  const u16* gB1 = gB0 + 64 * 1024;

  for (int k0 = 0; k0 < 1024; k0 += 32) {
    __syncthreads();
    gl_lds16(gA0 + k0, lA3 + wave * 512);
    gl_lds16(gA1 + k0, lA3 + 2048 + wave * 512);
    gl_lds16(gB0 + k0, lB3 + wave * 512);
    gl_lds16(gB1 + k0, lB3 + 2048 + wave * 512);
    __syncthreads();
    bf16x8 aF[4], bF[4];
#pragma unroll
    for (int mt = 0; mt < 4; mt++)
      aF[mt] = ldfrag(&lA[(wr * 64 + mt * 16 + l16) * 32 + qsw]);
#pragma unroll
    for (int nt = 0; nt < 4; nt++)
      bF[nt] = ldfrag(&lB[(wc * 64 + nt * 16 + l16) * 32 + qsw]);
#pragma unroll
    for (int mt = 0; mt < 4; mt++)
#pragma unroll
      for (int nt = 0; nt < 4; nt++)
        acc[mt][nt] = mfma16(aF[mt], bF[nt], acc[mt][nt]);
  }

#pragma unroll
  for (int mt = 0; mt < 4; mt++) {
#pragma unroll
    for (int nt = 0; nt < 4; nt++) {
#pragma unroll
      for (int r = 0; r < 4; r++) {
        int m = m0 + wr * 64 + mt * 16 + quad * 4 + r;
        int n = n0 + wc * 64 + nt * 16 + l16;
        out[(size_t)m * 1024 + n] = acc[mt][nt][r] + bias[n];
      }
    }
  }
}

extern "C" void kernel_launch(void* const* d_in, const int* in_sizes, int n_in,
                              void* d_out, int out_size, void* d_ws, size_t ws_size,
                              hipStream_t stream) {
  const float* x  = (const float*)d_in[0];
  const float* Wq = (const float*)d_in[1];
  const float* Wk = (const float*)d_in[2];
  const float* Wv = (const float*)d_in[3];
  const float* Wo = (const float*)d_in[4];
  const float* bo = (const float*)d_in[5];
  float* out = (float*)d_out;

  // ws (u16 elems), 40 MB total: xb/Ao | Wqkv | Wob | Qb.
  // d_out doubles as scratch for Kb+Vt (dead before gemm_out's fp32 write).
  u16* ws   = (u16*)d_ws;
  u16* xb   = ws;
  u16* Wqkv = ws + 8388608;
  u16* Wob  = ws + 11534336;
  u16* Qb   = ws + 12582912;
  u16* Ao   = xb;                       // lifetime-disjoint reuse
  u16* Kb   = (u16*)d_out;
  u16* Vt   = Kb + 8388608;

  cvt_all<<<12288, 256, 0, stream>>>(x, Wq, Wk, Wv, Wo, xb, Wqkv, Wob);
  gemm_qkv<<<dim3(24, 64), 256, 0, stream>>>(xb, Wqkv, Qb, Kb, Vt);
  attn<<<dim3(64, 8), 512, 0, stream>>>(Qb, Kb, Vt, Ao);
  gemm_out<<<dim3(8, 64), 256, 0, stream>>>(Ao, Wob, bo, out);
}